// Round 13
// baseline (556.762 us; speedup 1.0000x reference)
//
#include <hip/hip_runtime.h>
#include <hip/hip_bf16.h>
#include <hip/hip_cooperative_groups.h>
#include <cstdint>

namespace cg = cooperative_groups;

// Problem constants (match reference)
constexpr int N_NODES = 20000;
constexpr int N_EDGES = 500000;
constexpr int IN_F    = 64;
constexpr int OUT_F   = 64;
constexpr int KS      = 5;
constexpr int K_MATS  = 25;    // spline kernel matrices
constexpr int NK      = 26;    // + root weight
constexpr int ZTILE_USH = 1024;          // ushorts per (tile,k)
constexpr int ZBLKS = N_NODES / 16;      // 1250
constexpr int PREP_ITEMS = NK * 2 * 4 * 64;   // 53248
constexpr int PREP_BLOCKS = PREP_ITEMS / 256; // 208
constexpr int HIST_BLOCKS = (N_EDGES + 255) / 256;  // 1954

typedef __attribute__((ext_vector_type(8))) short short8;
typedef __attribute__((ext_vector_type(4))) float f32x4;

__device__ __forceinline__ ushort f2bf(float f) {   // RNE float->bf16 bits
    union { float f; uint32_t u; } c; c.f = f;
    uint32_t u = c.u + 0x7FFFu + ((c.u >> 16) & 1u);
    return (ushort)(u >> 16);
}
__device__ __forceinline__ float bf2f(uint32_t s) { // low 16 bits = bf16
    union { uint32_t u; float f; } c; c.u = (s & 0xFFFFu) << 16;
    return c.f;
}

// ===================== cooperative mega-kernel =====================
// Phase A: W-repack + degree histogram          (R12 k_ph bodies, grid-strided)
// Phase B: block0 = exclusive scan (T=256)  ||  blocks 1..: Z-GEMM tiles
// Phase C: per-edge basis -> sorted 16-B record (R12 k_fill body)
// Phase D: per-node gather-aggregate + epilogue (R12 k_out body, wave/node)
__global__ __launch_bounds__(256) void k_mega(
        const float* __restrict__ x, const int* __restrict__ ei,
        const float* __restrict__ pseudo, const float* __restrict__ weight,
        const float* __restrict__ bias, int* __restrict__ cnt,
        int* __restrict__ fill_pos, int* __restrict__ row_start,
        uint4* __restrict__ rec, ushort* __restrict__ wb,
        ushort* __restrict__ z, float* __restrict__ out) {
    cg::grid_group grid = cg::this_grid();
    __shared__ float lds[4][16][66];   // phase B (Z-GEMM bounce)
    __shared__ int   sums[256];        // phase B (scan)

    const int gt = blockIdx.x * 256 + threadIdx.x;
    const int gs = gridDim.x * 256;

    // ---------------- Phase A ----------------
    for (int t = gt; t < PREP_ITEMS; t += gs) {
        int lane = t & 63;
        int nf   = (t >> 6) & 3;
        int ks   = (t >> 8) & 1;
        int k    = t >> 9;
        int kk0  = ks * 32 + (lane >> 4) * 8;
        int col  = nf * 16 + (lane & 15);
        ushort v[8];
#pragma unroll
        for (int j = 0; j < 8; ++j)
            v[j] = f2bf(weight[(k * 64 + kk0 + j) * 64 + col]);
        uint4 p;
        p.x = (uint32_t)v[0] | ((uint32_t)v[1] << 16);
        p.y = (uint32_t)v[2] | ((uint32_t)v[3] << 16);
        p.z = (uint32_t)v[4] | ((uint32_t)v[5] << 16);
        p.w = (uint32_t)v[6] | ((uint32_t)v[7] << 16);
        ((uint4*)wb)[t] = p;
    }
    for (int e = gt; e < N_EDGES; e += gs)
        atomicAdd(&cnt[ei[e]], 1);
    __threadfence();
    grid.sync();

    // ---------------- Phase B ----------------
    if (blockIdx.x == 0) {
        const int T = 256;
        int tid = threadIdx.x;
        const int per = (N_NODES + T - 1) / T;   // 79
        int base = tid * per;
        int s = 0;
        for (int j = 0; j < per; ++j) {
            int idx = base + j;
            if (idx < N_NODES) s += cnt[idx];
        }
        sums[tid] = s;
        __syncthreads();
        for (int off = 1; off < T; off <<= 1) {
            int v = (tid >= off) ? sums[tid - off] : 0;
            __syncthreads();
            sums[tid] += v;
            __syncthreads();
        }
        int run = (tid == 0) ? 0 : sums[tid - 1];
        for (int j = 0; j < per; ++j) {
            int idx = base + j;
            if (idx < N_NODES) { row_start[idx] = run; run += cnt[idx]; }
        }
        if (tid == T - 1) row_start[N_NODES] = run;
    }
    if (blockIdx.x != 0 || gridDim.x == 1) {
        int tstart = (gridDim.x == 1) ? 0 : (int)blockIdx.x - 1;
        int tstride = (gridDim.x == 1) ? 1 : (int)gridDim.x - 1;
        int lane = threadIdx.x & 63;
        int wave = threadIdx.x >> 6;
        int r  = lane & 15;
        int kg = lane >> 4;
        for (int tile = tstart; tile < ZBLKS; tile += tstride) {
            int node0 = tile * 16;
            short8 a[2];
#pragma unroll
            for (int ks = 0; ks < 2; ++ks) {
                const float4* xp = (const float4*)(x + (node0 + r) * IN_F + ks * 32 + kg * 8);
                float4 x0 = xp[0];
                float4 x1 = xp[1];
                short8 af;
                af[0] = (short)f2bf(x0.x); af[1] = (short)f2bf(x0.y);
                af[2] = (short)f2bf(x0.z); af[3] = (short)f2bf(x0.w);
                af[4] = (short)f2bf(x1.x); af[5] = (short)f2bf(x1.y);
                af[6] = (short)f2bf(x1.z); af[7] = (short)f2bf(x1.w);
                a[ks] = af;
            }
            for (int k = wave; k < NK; k += 4) {
                f32x4 acc[4];
#pragma unroll
                for (int nf = 0; nf < 4; ++nf) acc[nf] = (f32x4){0.f, 0.f, 0.f, 0.f};
#pragma unroll
                for (int ks = 0; ks < 2; ++ks) {
#pragma unroll
                    for (int nf = 0; nf < 4; ++nf) {
                        union { uint4 u; short8 s; } b;
                        b.u = *(const uint4*)(wb + ((((size_t)k * 2 + ks) * 4 + nf) * 64 + lane) * 8);
                        acc[nf] = __builtin_amdgcn_mfma_f32_16x16x32_bf16(a[ks], b.s, acc[nf], 0, 0, 0);
                    }
                }
#pragma unroll
                for (int nf = 0; nf < 4; ++nf)
#pragma unroll
                    for (int rg = 0; rg < 4; ++rg)
                        lds[wave][kg * 4 + rg][nf * 16 + r] = acc[nf][rg];
                asm volatile("s_waitcnt lgkmcnt(0)" ::: "memory");
                __builtin_amdgcn_sched_barrier(0);
                const float* lrow = &lds[wave][lane >> 2][(lane & 3) * 16];
                float v[16];
#pragma unroll
                for (int j = 0; j < 16; ++j) v[j] = lrow[j];
                uint32_t pk[8];
#pragma unroll
                for (int j = 0; j < 8; ++j)
                    pk[j] = (uint32_t)f2bf(v[2 * j]) | ((uint32_t)f2bf(v[2 * j + 1]) << 16);
                uint4* dst = (uint4*)(z + (size_t)(tile * NK + k) * ZTILE_USH + lane * 16);
                dst[0] = make_uint4(pk[0], pk[1], pk[2], pk[3]);
                dst[1] = make_uint4(pk[4], pk[5], pk[6], pk[7]);
                asm volatile("" ::: "memory");
            }
        }
    }
    __threadfence();
    grid.sync();

    // ---------------- Phase C ----------------
    for (int e = gt; e < N_EDGES; e += gs) {
        int row = ei[e];
        int col = ei[N_EDGES + e];
        float u0 = pseudo[2 * e]     * (float)(KS - 1);
        float u1 = pseudo[2 * e + 1] * (float)(KS - 1);
        int i0 = min(max((int)floorf(u0), 0), KS - 2);
        int i1 = min(max((int)floorf(u1), 0), KS - 2);
        float f0 = u0 - (float)i0;
        float f1 = u1 - (float)i1;
        float b00 = (1.f - f0) * (1.f - f1);
        float b10 = f0 * (1.f - f1);
        float b01 = (1.f - f0) * f1;
        float b11 = f0 * f1;
        int k00 = i0 * KS + i1;
        int k10 = (i0 + 1) * KS + i1;
        int pos = row_start[row] + atomicAdd(&fill_pos[row], 1);
        uint4 rr;
        rr.x = (uint32_t)col;
        rr.y = (uint32_t)(k00 | (k10 << 8) | ((k00 + 1) << 16) | ((k10 + 1) << 24));
        rr.z = (uint32_t)f2bf(b00) | ((uint32_t)f2bf(b10) << 16);
        rr.w = (uint32_t)f2bf(b01) | ((uint32_t)f2bf(b11) << 16);
        rec[pos] = rr;
    }
    __threadfence();
    grid.sync();

    // ---------------- Phase D ----------------
    {
        int lane = threadIdx.x & 63;
        int wid = blockIdx.x * 4 + (threadIdx.x >> 6);
        int wstride = gridDim.x * 4;
        for (int n = wid; n < N_NODES; n += wstride) {
            int e0 = row_start[n], e1 = row_start[n + 1];
            float acc0 = 0.f, acc1 = 0.f;
            int e = e0;
            for (; e + 8 <= e1; e += 8) {
                uint4 rr[8];
#pragma unroll
                for (int t = 0; t < 8; ++t) rr[t] = rec[e + t];
                float vv[8][4];
#pragma unroll
                for (int t = 0; t < 8; ++t) {
                    uint32_t kp = rr[t].y;
                    uint32_t base = (rr[t].x >> 4) * (uint32_t)(NK * ZTILE_USH)
                                  + (rr[t].x & 15) * 64u + (uint32_t)lane;
                    vv[t][0] = bf2f((uint32_t)z[base + ((kp      ) & 255) * 1024u]);
                    vv[t][1] = bf2f((uint32_t)z[base + ((kp >> 8 ) & 255) * 1024u]);
                    vv[t][2] = bf2f((uint32_t)z[base + ((kp >> 16) & 255) * 1024u]);
                    vv[t][3] = bf2f((uint32_t)z[base + ((kp >> 24)      ) * 1024u]);
                }
#pragma unroll
                for (int t = 0; t < 8; ++t) {
                    float b0 = bf2f(rr[t].z), b1 = bf2f(rr[t].z >> 16);
                    float b2 = bf2f(rr[t].w), b3 = bf2f(rr[t].w >> 16);
                    float s = b0 * vv[t][0] + b1 * vv[t][1] + b2 * vv[t][2] + b3 * vv[t][3];
                    if (t & 1) acc1 += s; else acc0 += s;
                }
            }
            for (; e + 4 <= e1; e += 4) {
                uint4 rr[4];
#pragma unroll
                for (int t = 0; t < 4; ++t) rr[t] = rec[e + t];
                float vv[4][4];
#pragma unroll
                for (int t = 0; t < 4; ++t) {
                    uint32_t kp = rr[t].y;
                    uint32_t base = (rr[t].x >> 4) * (uint32_t)(NK * ZTILE_USH)
                                  + (rr[t].x & 15) * 64u + (uint32_t)lane;
                    vv[t][0] = bf2f((uint32_t)z[base + ((kp      ) & 255) * 1024u]);
                    vv[t][1] = bf2f((uint32_t)z[base + ((kp >> 8 ) & 255) * 1024u]);
                    vv[t][2] = bf2f((uint32_t)z[base + ((kp >> 16) & 255) * 1024u]);
                    vv[t][3] = bf2f((uint32_t)z[base + ((kp >> 24)      ) * 1024u]);
                }
#pragma unroll
                for (int t = 0; t < 4; ++t) {
                    float b0 = bf2f(rr[t].z), b1 = bf2f(rr[t].z >> 16);
                    float b2 = bf2f(rr[t].w), b3 = bf2f(rr[t].w >> 16);
                    float s = b0 * vv[t][0] + b1 * vv[t][1] + b2 * vv[t][2] + b3 * vv[t][3];
                    if (t & 1) acc1 += s; else acc0 += s;
                }
            }
            for (; e < e1; ++e) {
                uint4 r = rec[e];
                uint32_t kp = r.y;
                uint32_t base = (r.x >> 4) * (uint32_t)(NK * ZTILE_USH)
                              + (r.x & 15) * 64u + (uint32_t)lane;
                float v0 = bf2f((uint32_t)z[base + ((kp      ) & 255) * 1024u]);
                float v1 = bf2f((uint32_t)z[base + ((kp >> 8 ) & 255) * 1024u]);
                float v2 = bf2f((uint32_t)z[base + ((kp >> 16) & 255) * 1024u]);
                float v3 = bf2f((uint32_t)z[base + ((kp >> 24)      ) * 1024u]);
                acc0 += bf2f(r.z) * v0 + bf2f(r.z >> 16) * v1
                      + bf2f(r.w) * v2 + bf2f(r.w >> 16) * v3;
            }
            int deg = e1 - e0;
            uint32_t rbase = ((uint32_t)(n >> 4) * NK + K_MATS) * (uint32_t)ZTILE_USH
                           + (uint32_t)(n & 15) * 64u + (uint32_t)lane;
            float root = bf2f((uint32_t)z[rbase]);
            out[n * OUT_F + lane] = (acc0 + acc1) / (float)max(deg, 1) + root + bias[lane];
        }
    }
}

// ===================== R12 fallback kernels (proven, 209 µs) ================

__global__ void k_ph(const float* __restrict__ w, ushort* __restrict__ wb,
                     const int* __restrict__ ei, int* __restrict__ cnt) {
    int b = blockIdx.x;
    if (b < PREP_BLOCKS) {
        int t = b * 256 + threadIdx.x;
        int lane = t & 63;
        int nf   = (t >> 6) & 3;
        int ks   = (t >> 8) & 1;
        int k    = t >> 9;
        int kk0  = ks * 32 + (lane >> 4) * 8;
        int col  = nf * 16 + (lane & 15);
        ushort v[8];
#pragma unroll
        for (int j = 0; j < 8; ++j)
            v[j] = f2bf(w[(k * 64 + kk0 + j) * 64 + col]);
        uint4 p;
        p.x = (uint32_t)v[0] | ((uint32_t)v[1] << 16);
        p.y = (uint32_t)v[2] | ((uint32_t)v[3] << 16);
        p.z = (uint32_t)v[4] | ((uint32_t)v[5] << 16);
        p.w = (uint32_t)v[6] | ((uint32_t)v[7] << 16);
        ((uint4*)wb)[t] = p;
    } else {
        int e = (b - PREP_BLOCKS) * 256 + threadIdx.x;
        if (e < N_EDGES) atomicAdd(&cnt[ei[e]], 1);
    }
}

__global__ __launch_bounds__(1024) void k_scan(const int* __restrict__ cnt,
                                               int* __restrict__ row_start) {
    __shared__ int sums[1024];
    const int T = 1024;
    int tid = threadIdx.x;
    const int per = (N_NODES + T - 1) / T;
    int base = tid * per;
    int s = 0;
    for (int j = 0; j < per; ++j) {
        int idx = base + j;
        if (idx < N_NODES) s += cnt[idx];
    }
    sums[tid] = s;
    __syncthreads();
    for (int off = 1; off < T; off <<= 1) {
        int v = (tid >= off) ? sums[tid - off] : 0;
        __syncthreads();
        sums[tid] += v;
        __syncthreads();
    }
    int run = (tid == 0) ? 0 : sums[tid - 1];
    for (int j = 0; j < per; ++j) {
        int idx = base + j;
        if (idx < N_NODES) { row_start[idx] = run; run += cnt[idx]; }
    }
    if (tid == T - 1) row_start[N_NODES] = run;
}

__global__ void k_fill(const int* __restrict__ ei, const float* __restrict__ pseudo,
                       const int* __restrict__ row_start, int* __restrict__ fill_pos,
                       uint4* __restrict__ rec) {
    int e = blockIdx.x * blockDim.x + threadIdx.x;
    if (e >= N_EDGES) return;
    int row = ei[e];
    int col = ei[N_EDGES + e];
    float u0 = pseudo[2 * e]     * (float)(KS - 1);
    float u1 = pseudo[2 * e + 1] * (float)(KS - 1);
    int i0 = min(max((int)floorf(u0), 0), KS - 2);
    int i1 = min(max((int)floorf(u1), 0), KS - 2);
    float f0 = u0 - (float)i0;
    float f1 = u1 - (float)i1;
    float b00 = (1.f - f0) * (1.f - f1);
    float b10 = f0 * (1.f - f1);
    float b01 = (1.f - f0) * f1;
    float b11 = f0 * f1;
    int k00 = i0 * KS + i1;
    int k10 = (i0 + 1) * KS + i1;
    int pos = row_start[row] + atomicAdd(&fill_pos[row], 1);
    uint4 r;
    r.x = (uint32_t)col;
    r.y = (uint32_t)(k00 | (k10 << 8) | ((k00 + 1) << 16) | ((k10 + 1) << 24));
    r.z = (uint32_t)f2bf(b00) | ((uint32_t)f2bf(b10) << 16);
    r.w = (uint32_t)f2bf(b01) | ((uint32_t)f2bf(b11) << 16);
    rec[pos] = r;
}

__global__ __launch_bounds__(256) void k_z(const float* __restrict__ x,
                                           const ushort* __restrict__ wb,
                                           ushort* __restrict__ z) {
    __shared__ float lds[4][16][66];
    int lane = threadIdx.x & 63;
    int wave = threadIdx.x >> 6;
    int tile = blockIdx.x;
    int node0 = tile * 16;
    int r  = lane & 15;
    int kg = lane >> 4;

    short8 a[2];
#pragma unroll
    for (int ks = 0; ks < 2; ++ks) {
        const float4* xp = (const float4*)(x + (node0 + r) * IN_F + ks * 32 + kg * 8);
        float4 x0 = xp[0];
        float4 x1 = xp[1];
        short8 af;
        af[0] = (short)f2bf(x0.x); af[1] = (short)f2bf(x0.y);
        af[2] = (short)f2bf(x0.z); af[3] = (short)f2bf(x0.w);
        af[4] = (short)f2bf(x1.x); af[5] = (short)f2bf(x1.y);
        af[6] = (short)f2bf(x1.z); af[7] = (short)f2bf(x1.w);
        a[ks] = af;
    }

    for (int k = wave; k < NK; k += 4) {
        f32x4 acc[4];
#pragma unroll
        for (int nf = 0; nf < 4; ++nf) acc[nf] = (f32x4){0.f, 0.f, 0.f, 0.f};
#pragma unroll
        for (int ks = 0; ks < 2; ++ks) {
#pragma unroll
            for (int nf = 0; nf < 4; ++nf) {
                union { uint4 u; short8 s; } b;
                b.u = *(const uint4*)(wb + ((((size_t)k * 2 + ks) * 4 + nf) * 64 + lane) * 8);
                acc[nf] = __builtin_amdgcn_mfma_f32_16x16x32_bf16(a[ks], b.s, acc[nf], 0, 0, 0);
            }
        }
#pragma unroll
        for (int nf = 0; nf < 4; ++nf)
#pragma unroll
            for (int rg = 0; rg < 4; ++rg)
                lds[wave][kg * 4 + rg][nf * 16 + r] = acc[nf][rg];
        asm volatile("s_waitcnt lgkmcnt(0)" ::: "memory");
        __builtin_amdgcn_sched_barrier(0);
        const float* lrow = &lds[wave][lane >> 2][(lane & 3) * 16];
        float v[16];
#pragma unroll
        for (int j = 0; j < 16; ++j) v[j] = lrow[j];
        uint32_t pk[8];
#pragma unroll
        for (int j = 0; j < 8; ++j)
            pk[j] = (uint32_t)f2bf(v[2 * j]) | ((uint32_t)f2bf(v[2 * j + 1]) << 16);
        uint4* dst = (uint4*)(z + (size_t)(tile * NK + k) * ZTILE_USH + lane * 16);
        dst[0] = make_uint4(pk[0], pk[1], pk[2], pk[3]);
        dst[1] = make_uint4(pk[4], pk[5], pk[6], pk[7]);
        asm volatile("" ::: "memory");
    }
}

__global__ __launch_bounds__(256) void k_out(const ushort* __restrict__ z,
        const float* __restrict__ bias, const int* __restrict__ row_start,
        const uint4* __restrict__ rec, float* __restrict__ out) {
    int lane = threadIdx.x & 63;
    int n = blockIdx.x * 4 + (threadIdx.x >> 6);
    if (n >= N_NODES) return;
    int e0 = row_start[n], e1 = row_start[n + 1];
    float acc0 = 0.f, acc1 = 0.f;
    int e = e0;
    for (; e + 8 <= e1; e += 8) {
        uint4 rr[8];
#pragma unroll
        for (int t = 0; t < 8; ++t) rr[t] = rec[e + t];
        float vv[8][4];
#pragma unroll
        for (int t = 0; t < 8; ++t) {
            uint32_t kp = rr[t].y;
            uint32_t base = (rr[t].x >> 4) * (uint32_t)(NK * ZTILE_USH)
                          + (rr[t].x & 15) * 64u + (uint32_t)lane;
            vv[t][0] = bf2f((uint32_t)z[base + ((kp      ) & 255) * 1024u]);
            vv[t][1] = bf2f((uint32_t)z[base + ((kp >> 8 ) & 255) * 1024u]);
            vv[t][2] = bf2f((uint32_t)z[base + ((kp >> 16) & 255) * 1024u]);
            vv[t][3] = bf2f((uint32_t)z[base + ((kp >> 24)      ) * 1024u]);
        }
#pragma unroll
        for (int t = 0; t < 8; ++t) {
            float b0 = bf2f(rr[t].z), b1 = bf2f(rr[t].z >> 16);
            float b2 = bf2f(rr[t].w), b3 = bf2f(rr[t].w >> 16);
            float s = b0 * vv[t][0] + b1 * vv[t][1] + b2 * vv[t][2] + b3 * vv[t][3];
            if (t & 1) acc1 += s; else acc0 += s;
        }
    }
    for (; e + 4 <= e1; e += 4) {
        uint4 rr[4];
#pragma unroll
        for (int t = 0; t < 4; ++t) rr[t] = rec[e + t];
        float vv[4][4];
#pragma unroll
        for (int t = 0; t < 4; ++t) {
            uint32_t kp = rr[t].y;
            uint32_t base = (rr[t].x >> 4) * (uint32_t)(NK * ZTILE_USH)
                          + (rr[t].x & 15) * 64u + (uint32_t)lane;
            vv[t][0] = bf2f((uint32_t)z[base + ((kp      ) & 255) * 1024u]);
            vv[t][1] = bf2f((uint32_t)z[base + ((kp >> 8 ) & 255) * 1024u]);
            vv[t][2] = bf2f((uint32_t)z[base + ((kp >> 16) & 255) * 1024u]);
            vv[t][3] = bf2f((uint32_t)z[base + ((kp >> 24)      ) * 1024u]);
        }
#pragma unroll
        for (int t = 0; t < 4; ++t) {
            float b0 = bf2f(rr[t].z), b1 = bf2f(rr[t].z >> 16);
            float b2 = bf2f(rr[t].w), b3 = bf2f(rr[t].w >> 16);
            float s = b0 * vv[t][0] + b1 * vv[t][1] + b2 * vv[t][2] + b3 * vv[t][3];
            if (t & 1) acc1 += s; else acc0 += s;
        }
    }
    for (; e < e1; ++e) {
        uint4 r = rec[e];
        uint32_t kp = r.y;
        uint32_t base = (r.x >> 4) * (uint32_t)(NK * ZTILE_USH)
                      + (r.x & 15) * 64u + (uint32_t)lane;
        float v0 = bf2f((uint32_t)z[base + ((kp      ) & 255) * 1024u]);
        float v1 = bf2f((uint32_t)z[base + ((kp >> 8 ) & 255) * 1024u]);
        float v2 = bf2f((uint32_t)z[base + ((kp >> 16) & 255) * 1024u]);
        float v3 = bf2f((uint32_t)z[base + ((kp >> 24)      ) * 1024u]);
        acc0 += bf2f(r.z) * v0 + bf2f(r.z >> 16) * v1
              + bf2f(r.w) * v2 + bf2f(r.w >> 16) * v3;
    }
    int deg = e1 - e0;
    uint32_t rbase = ((uint32_t)(n >> 4) * NK + K_MATS) * (uint32_t)ZTILE_USH
                   + (uint32_t)(n & 15) * 64u + (uint32_t)lane;
    float root = bf2f((uint32_t)z[rbase]);
    out[n * OUT_F + lane] = (acc0 + acc1) / (float)max(deg, 1) + root + bias[lane];
}

// ---------------- launch ----------------

extern "C" void kernel_launch(void* const* d_in, const int* in_sizes, int n_in,
                              void* d_out, int out_size, void* d_ws, size_t ws_size,
                              hipStream_t stream) {
    const float* x      = (const float*)d_in[0];
    const int*   ei     = (const int*)d_in[1];
    const float* pseudo = (const float*)d_in[2];
    const float* weight = (const float*)d_in[3];
    const float* bias   = (const float*)d_in[4];
    float* out = (float*)d_out;

    // workspace layout (bytes); ~75 MB total (proven to fit)
    char* ws = (char*)d_ws;
    int* cnt       = (int*)(ws + 0);            // N ints
    int* fill_pos  = (int*)(ws + 80000);        // N ints
    int* row_start = (int*)(ws + 160000);       // N+1 ints
    uint4* rec     = (uint4*)(ws + 240128);     // E * 16 B          -> ends 8240128
    ushort* wb     = (ushort*)(ws + 8240128);   // 26*2*4*64*16 B    -> ends 8453120
    ushort* zb     = (ushort*)(ws + 8453120);   // 1250*26*2048 B    -> ends ~75 MB

    hipMemsetAsync(ws, 0, 160000, stream);      // cnt + fill_pos

    // Cooperative mega-kernel; fall back to the proven 5-dispatch path if
    // cooperative launch is unsupported (incl. under graph capture).
    int nb = 0;
    hipError_t oerr = hipOccupancyMaxActiveBlocksPerMultiprocessor(&nb, k_mega, 256, 0);
    if (oerr != hipSuccess || nb < 1) nb = 2;
    int grid = nb * 256;                         // 256 CUs on gfx950
    if (grid < 2) grid = 2;

    void* args[] = { (void*)&x, (void*)&ei, (void*)&pseudo, (void*)&weight,
                     (void*)&bias, (void*)&cnt, (void*)&fill_pos, (void*)&row_start,
                     (void*)&rec, (void*)&wb, (void*)&zb, (void*)&out };
    hipError_t lerr = hipLaunchCooperativeKernel((const void*)k_mega, dim3(grid),
                                                 dim3(256), args, 0, stream);
    if (lerr != hipSuccess) {
        k_ph<<<PREP_BLOCKS + HIST_BLOCKS, 256, 0, stream>>>(weight, wb, ei, cnt);
        k_scan<<<1, 1024, 0, stream>>>(cnt, row_start);
        k_fill<<<HIST_BLOCKS, 256, 0, stream>>>(ei, pseudo, row_start, fill_pos, rec);
        k_z<<<ZBLKS, 256, 0, stream>>>(x, wb, zb);
        k_out<<<(N_NODES + 3) / 4, 256, 0, stream>>>(zb, bias, row_start, rec, out);
    }
}

// Round 15
// 226.523 us; speedup vs baseline: 2.4579x; 2.4579x over previous
//
#include <hip/hip_runtime.h>
#include <hip/hip_bf16.h>
#include <cstdint>

// Problem constants (match reference)
constexpr int N_NODES = 20000;
constexpr int N_EDGES = 500000;
constexpr int IN_F    = 64;
constexpr int OUT_F   = 64;
constexpr int KS      = 5;
constexpr int K_MATS  = 25;    // spline kernel matrices
constexpr int NK      = 26;    // + root weight
// Z layout: [node/16][k][node%16][64ch] bf16 -> 2048 B per (tile,k) region
constexpr int ZTILE_USH = 1024;          // ushorts per (tile,k)
constexpr int ZBLKS = N_NODES / 16;      // 1250
constexpr int PREP_BLOCKS = (NK * 2 * 4 * 64) / 256;       // 208
constexpr int HIST_BLOCKS = (N_EDGES + 255) / 256;         // 1954

// R13 lesson: cooperative mega-kernel = 556 µs (grid capped at co-residency
// kills TLP; grid.sync expensive). R6-vs-R12 comparison: dispatch overhead
// ~0 µs. The ~165 µs outside k_out is real kernel time in {k_ph,k_fill,k_z}.
// This round: R12 pipeline verbatim + k_out split into 4 quarter-dispatches
// so the largest hidden kernel surfaces in top-5 with full counters.

typedef __attribute__((ext_vector_type(8))) short short8;
typedef __attribute__((ext_vector_type(4))) float f32x4;

__device__ __forceinline__ ushort f2bf(float f) {   // RNE float->bf16 bits
    union { float f; uint32_t u; } c; c.f = f;
    uint32_t u = c.u + 0x7FFFu + ((c.u >> 16) & 1u);
    return (ushort)(u >> 16);
}
__device__ __forceinline__ float bf2f(uint32_t s) { // low 16 bits = bf16
    union { uint32_t u; float f; } c; c.u = (s & 0xFFFFu) << 16;
    return c.f;
}

// ---------------- fused W-repack + degree histogram (R6/R12-proven) --------
__global__ void k_ph(const float* __restrict__ w, ushort* __restrict__ wb,
                     const int* __restrict__ ei, int* __restrict__ cnt) {
    int b = blockIdx.x;
    if (b < PREP_BLOCKS) {
        int t = b * 256 + threadIdx.x;   // one 16B B-frag slot
        int lane = t & 63;
        int nf   = (t >> 6) & 3;
        int ks   = (t >> 8) & 1;
        int k    = t >> 9;
        int kk0  = ks * 32 + (lane >> 4) * 8;
        int col  = nf * 16 + (lane & 15);
        ushort v[8];
#pragma unroll
        for (int j = 0; j < 8; ++j)
            v[j] = f2bf(w[(k * 64 + kk0 + j) * 64 + col]);
        uint4 p;
        p.x = (uint32_t)v[0] | ((uint32_t)v[1] << 16);
        p.y = (uint32_t)v[2] | ((uint32_t)v[3] << 16);
        p.z = (uint32_t)v[4] | ((uint32_t)v[5] << 16);
        p.w = (uint32_t)v[6] | ((uint32_t)v[7] << 16);
        ((uint4*)wb)[t] = p;
    } else {
        int e = (b - PREP_BLOCKS) * 256 + threadIdx.x;
        if (e < N_EDGES) atomicAdd(&cnt[ei[e]], 1);
    }
}

// ---------------- exclusive scan (single block, R12-proven) ----------------
__global__ __launch_bounds__(1024) void k_scan(const int* __restrict__ cnt,
                                               int* __restrict__ row_start) {
    __shared__ int sums[1024];
    const int T = 1024;
    int tid = threadIdx.x;
    const int per = (N_NODES + T - 1) / T;   // 20
    int base = tid * per;
    int s = 0;
    for (int j = 0; j < per; ++j) {
        int idx = base + j;
        if (idx < N_NODES) s += cnt[idx];
    }
    sums[tid] = s;
    __syncthreads();
    for (int off = 1; off < T; off <<= 1) {
        int v = (tid >= off) ? sums[tid - off] : 0;
        __syncthreads();
        sums[tid] += v;
        __syncthreads();
    }
    int run = (tid == 0) ? 0 : sums[tid - 1];
    for (int j = 0; j < per; ++j) {
        int idx = base + j;
        if (idx < N_NODES) { row_start[idx] = run; run += cnt[idx]; }
    }
    if (tid == T - 1) row_start[N_NODES] = run;
}

// ---------------- per-edge basis -> 16-B sorted record (R12-proven) --------
__global__ void k_fill(const int* __restrict__ ei, const float* __restrict__ pseudo,
                       const int* __restrict__ row_start, int* __restrict__ fill_pos,
                       uint4* __restrict__ rec) {
    int e = blockIdx.x * blockDim.x + threadIdx.x;
    if (e >= N_EDGES) return;
    int row = ei[e];
    int col = ei[N_EDGES + e];
    float u0 = pseudo[2 * e]     * (float)(KS - 1);
    float u1 = pseudo[2 * e + 1] * (float)(KS - 1);
    int i0 = min(max((int)floorf(u0), 0), KS - 2);
    int i1 = min(max((int)floorf(u1), 0), KS - 2);
    float f0 = u0 - (float)i0;
    float f1 = u1 - (float)i1;
    float b00 = (1.f - f0) * (1.f - f1);
    float b10 = f0 * (1.f - f1);
    float b01 = (1.f - f0) * f1;
    float b11 = f0 * f1;
    int k00 = i0 * KS + i1;
    int k10 = (i0 + 1) * KS + i1;
    int pos = row_start[row] + atomicAdd(&fill_pos[row], 1);
    uint4 r;
    r.x = (uint32_t)col;
    r.y = (uint32_t)(k00 | (k10 << 8) | ((k00 + 1) << 16) | ((k10 + 1) << 24));
    r.z = (uint32_t)f2bf(b00) | ((uint32_t)f2bf(b10) << 16);
    r.w = (uint32_t)f2bf(b01) | ((uint32_t)f2bf(b11) << 16);
    rec[pos] = r;
}

// ---------------- Z = x @ W[k] via MFMA (R12-proven) ----------------
__global__ __launch_bounds__(256) void k_z(const float* __restrict__ x,
                                           const ushort* __restrict__ wb,
                                           ushort* __restrict__ z) {
    __shared__ float lds[4][16][66];   // per-wave bounce, stride 66
    int lane = threadIdx.x & 63;
    int wave = threadIdx.x >> 6;
    int tile = blockIdx.x;
    int node0 = tile * 16;
    int r  = lane & 15;
    int kg = lane >> 4;

    short8 a[2];
#pragma unroll
    for (int ks = 0; ks < 2; ++ks) {
        const float4* xp = (const float4*)(x + (node0 + r) * IN_F + ks * 32 + kg * 8);
        float4 x0 = xp[0];
        float4 x1 = xp[1];
        short8 af;
        af[0] = (short)f2bf(x0.x); af[1] = (short)f2bf(x0.y);
        af[2] = (short)f2bf(x0.z); af[3] = (short)f2bf(x0.w);
        af[4] = (short)f2bf(x1.x); af[5] = (short)f2bf(x1.y);
        af[6] = (short)f2bf(x1.z); af[7] = (short)f2bf(x1.w);
        a[ks] = af;
    }

    for (int k = wave; k < NK; k += 4) {
        f32x4 acc[4];
#pragma unroll
        for (int nf = 0; nf < 4; ++nf) acc[nf] = (f32x4){0.f, 0.f, 0.f, 0.f};
#pragma unroll
        for (int ks = 0; ks < 2; ++ks) {
#pragma unroll
            for (int nf = 0; nf < 4; ++nf) {
                union { uint4 u; short8 s; } b;
                b.u = *(const uint4*)(wb + ((((size_t)k * 2 + ks) * 4 + nf) * 64 + lane) * 8);
                acc[nf] = __builtin_amdgcn_mfma_f32_16x16x32_bf16(a[ks], b.s, acc[nf], 0, 0, 0);
            }
        }
        // D-frag (row = 4*kg + rg, col = nf*16 + r) -> per-wave LDS tile
#pragma unroll
        for (int nf = 0; nf < 4; ++nf)
#pragma unroll
            for (int rg = 0; rg < 4; ++rg)
                lds[wave][kg * 4 + rg][nf * 16 + r] = acc[nf][rg];
        asm volatile("s_waitcnt lgkmcnt(0)" ::: "memory");
        __builtin_amdgcn_sched_barrier(0);
        const float* lrow = &lds[wave][lane >> 2][(lane & 3) * 16];
        float v[16];
#pragma unroll
        for (int j = 0; j < 16; ++j) v[j] = lrow[j];
        uint32_t pk[8];
#pragma unroll
        for (int j = 0; j < 8; ++j)
            pk[j] = (uint32_t)f2bf(v[2 * j]) | ((uint32_t)f2bf(v[2 * j + 1]) << 16);
        uint4* dst = (uint4*)(z + (size_t)(tile * NK + k) * ZTILE_USH + lane * 16);
        dst[0] = make_uint4(pk[0], pk[1], pk[2], pk[3]);
        dst[1] = make_uint4(pk[4], pk[5], pk[6], pk[7]);
        asm volatile("" ::: "memory");
    }
}

// ---------------- Per-node gather-aggregate + epilogue (R12-proven) --------
// Identical code path; n0base param lets us launch 4 quarter-dispatches so
// the hidden CSR/Z kernels surface in the top-5 profile.
__global__ __launch_bounds__(256) void k_out(const ushort* __restrict__ z,
        const float* __restrict__ bias, const int* __restrict__ row_start,
        const uint4* __restrict__ rec, float* __restrict__ out, int n0base) {
    int lane = threadIdx.x & 63;
    int n = n0base + blockIdx.x * 4 + (threadIdx.x >> 6);
    if (n >= N_NODES) return;
    int e0 = row_start[n], e1 = row_start[n + 1];
    float acc0 = 0.f, acc1 = 0.f;
    int e = e0;
    for (; e + 8 <= e1; e += 8) {
        uint4 rr[8];
#pragma unroll
        for (int t = 0; t < 8; ++t) rr[t] = rec[e + t];
        float vv[8][4];
#pragma unroll
        for (int t = 0; t < 8; ++t) {
            uint32_t kp = rr[t].y;
            uint32_t base = (rr[t].x >> 4) * (uint32_t)(NK * ZTILE_USH)
                          + (rr[t].x & 15) * 64u + (uint32_t)lane;
            vv[t][0] = bf2f((uint32_t)z[base + ((kp      ) & 255) * 1024u]);
            vv[t][1] = bf2f((uint32_t)z[base + ((kp >> 8 ) & 255) * 1024u]);
            vv[t][2] = bf2f((uint32_t)z[base + ((kp >> 16) & 255) * 1024u]);
            vv[t][3] = bf2f((uint32_t)z[base + ((kp >> 24)      ) * 1024u]);
        }
#pragma unroll
        for (int t = 0; t < 8; ++t) {
            float b0 = bf2f(rr[t].z), b1 = bf2f(rr[t].z >> 16);
            float b2 = bf2f(rr[t].w), b3 = bf2f(rr[t].w >> 16);
            float s = b0 * vv[t][0] + b1 * vv[t][1] + b2 * vv[t][2] + b3 * vv[t][3];
            if (t & 1) acc1 += s; else acc0 += s;
        }
    }
    for (; e + 4 <= e1; e += 4) {
        uint4 rr[4];
#pragma unroll
        for (int t = 0; t < 4; ++t) rr[t] = rec[e + t];
        float vv[4][4];
#pragma unroll
        for (int t = 0; t < 4; ++t) {
            uint32_t kp = rr[t].y;
            uint32_t base = (rr[t].x >> 4) * (uint32_t)(NK * ZTILE_USH)
                          + (rr[t].x & 15) * 64u + (uint32_t)lane;
            vv[t][0] = bf2f((uint32_t)z[base + ((kp      ) & 255) * 1024u]);
            vv[t][1] = bf2f((uint32_t)z[base + ((kp >> 8 ) & 255) * 1024u]);
            vv[t][2] = bf2f((uint32_t)z[base + ((kp >> 16) & 255) * 1024u]);
            vv[t][3] = bf2f((uint32_t)z[base + ((kp >> 24)      ) * 1024u]);
        }
#pragma unroll
        for (int t = 0; t < 4; ++t) {
            float b0 = bf2f(rr[t].z), b1 = bf2f(rr[t].z >> 16);
            float b2 = bf2f(rr[t].w), b3 = bf2f(rr[t].w >> 16);
            float s = b0 * vv[t][0] + b1 * vv[t][1] + b2 * vv[t][2] + b3 * vv[t][3];
            if (t & 1) acc1 += s; else acc0 += s;
        }
    }
    for (; e < e1; ++e) {
        uint4 r = rec[e];
        uint32_t kp = r.y;
        uint32_t base = (r.x >> 4) * (uint32_t)(NK * ZTILE_USH)
                      + (r.x & 15) * 64u + (uint32_t)lane;
        float v0 = bf2f((uint32_t)z[base + ((kp      ) & 255) * 1024u]);
        float v1 = bf2f((uint32_t)z[base + ((kp >> 8 ) & 255) * 1024u]);
        float v2 = bf2f((uint32_t)z[base + ((kp >> 16) & 255) * 1024u]);
        float v3 = bf2f((uint32_t)z[base + ((kp >> 24)      ) * 1024u]);
        acc0 += bf2f(r.z) * v0 + bf2f(r.z >> 16) * v1
              + bf2f(r.w) * v2 + bf2f(r.w >> 16) * v3;
    }
    int deg = e1 - e0;
    uint32_t rbase = ((uint32_t)(n >> 4) * NK + K_MATS) * (uint32_t)ZTILE_USH
                   + (uint32_t)(n & 15) * 64u + (uint32_t)lane;
    float root = bf2f((uint32_t)z[rbase]);
    out[n * OUT_F + lane] = (acc0 + acc1) / (float)max(deg, 1) + root + bias[lane];
}

// ---------------- launch (R12 structure; k_out split 4-way) ----------------

extern "C" void kernel_launch(void* const* d_in, const int* in_sizes, int n_in,
                              void* d_out, int out_size, void* d_ws, size_t ws_size,
                              hipStream_t stream) {
    const float* x      = (const float*)d_in[0];
    const int*   ei     = (const int*)d_in[1];
    const float* pseudo = (const float*)d_in[2];
    const float* weight = (const float*)d_in[3];
    const float* bias   = (const float*)d_in[4];
    float* out = (float*)d_out;

    // workspace layout (bytes); ~75 MB total (proven to fit)
    char* ws = (char*)d_ws;
    int* cnt       = (int*)(ws + 0);            // N ints
    int* fill_pos  = (int*)(ws + 80000);        // N ints
    int* row_start = (int*)(ws + 160000);       // N+1 ints
    uint4* rec     = (uint4*)(ws + 240128);     // E * 16 B          -> ends 8240128
    ushort* wb     = (ushort*)(ws + 8240128);   // 26*2*4*64*16 B    -> ends 8453120
    ushort* zb     = (ushort*)(ws + 8453120);   // 1250*26*2048 B    -> ends ~75 MB

    hipMemsetAsync(ws, 0, 160000, stream);      // cnt + fill_pos

    k_ph<<<PREP_BLOCKS + HIST_BLOCKS, 256, 0, stream>>>(weight, wb, ei, cnt);
    k_scan<<<1, 1024, 0, stream>>>(cnt, row_start);
    k_fill<<<HIST_BLOCKS, 256, 0, stream>>>(ei, pseudo, row_start, fill_pos, rec);
    k_z<<<ZBLKS, 256, 0, stream>>>(x, wb, zb);
    // k_out split into 4 quarter-dispatches (5000 nodes each, same code path)
    for (int q = 0; q < 4; ++q)
        k_out<<<1250, 256, 0, stream>>>(zb, bias, row_start, rec, out, q * 5000);
}